// Round 6
// baseline (202.792 us; speedup 1.0000x reference)
//
#include <hip/hip_runtime.h>

#define N_NODES 100000
#define N_EDGES 600000
#define D 128
#define MAXDEG 64
#define OVF_CAP 4096
#define BM 32

typedef __attribute__((ext_vector_type(8))) short bf16x8;
typedef __attribute__((ext_vector_type(4))) float f32x4;
typedef __attribute__((ext_vector_type(2))) float f32x2;

static __device__ inline ushort f2bf(float f) {
    unsigned x = __float_as_uint(f);
    unsigned r = (x + 0x7fffu + ((x >> 16) & 1u)) >> 16;  // RNE
    return (ushort)r;
}
static __device__ inline float bf2f(ushort u) {
    return __uint_as_float((unsigned)u << 16);
}
static __device__ inline f32x2 nt_load2(const float* p) {
    return __builtin_nontemporal_load((const f32x2*)p);
}
static __device__ inline unsigned mulpack2(unsigned a, float dv) {
    return (unsigned)f2bf(dv * bf2f((ushort)a)) |
           ((unsigned)f2bf(dv * bf2f((ushort)(a >> 16))) << 16);
}

// ws layout (byte offsets):
//   0          Wfrag  ushort[512*128]   bf16 fused weight, MFMA B-frag order
//   131072     Wcat32 float[512*128]    fp32 fused weight (overflow path)
//   393216     bv     float[128]
//   393728     deg    float[N]
//   793728     cnt    int[N+1] (+pad)
//   1193984    ovf    int[OVF_CAP]
//   1210368    elist2 int2[N*MAXDEG]
//   52410368   h16    ushort[N*128]     bf16 copy of h
//   78010368   Sea16  ushort[N*256]     per-node [S | Ea] in bf16
//
// out[n] = [h[n] | S[n] | deg[n]*h[n] | Ea[n]] @ Wcat + deg[n]*bv + b_upd
// Wfrag[(kb*8+cb)*512 + l*8 + i] = Wcat[kb*32+(l>>4)*8+i][cb*16+(l&15)]
// Wcat rows: 0..127 = Wu1; 128..255 = W1@Wu2; 256..383 = W2@Wu2; 384..511 = W3@Wu2

__global__ void k_zero(int* __restrict__ cnt) {
    int i = blockIdx.x * 256 + threadIdx.x;
    if (i < N_NODES + 1) cnt[i] = 0;
}

__global__ void k_build_w(const float* __restrict__ W_msg,
                          const float* __restrict__ b_msg,
                          const float* __restrict__ W_upd,
                          ushort* __restrict__ Wfrag,
                          float* __restrict__ Wcat32,
                          float* __restrict__ bv)
{
    int gid = blockIdx.x * 256 + threadIdx.x;
    if (gid < 512 * 128) {
        int i = gid & 7;
        int l = (gid >> 3) & 63;
        int fb = gid >> 9;          // kb*8 + cb
        int kb = fb >> 3, cb = fb & 7;
        int k = kb * 32 + ((l >> 4) * 8) + i;
        int j = cb * 16 + (l & 15);
        float acc;
        if (k < 128) {
            acc = W_upd[k * 128 + j];
        } else {
            int r = k - 128;
            acc = 0.f;
            #pragma unroll 4
            for (int dd = 0; dd < 128; ++dd)
                acc += W_msg[r * 128 + dd] * W_upd[(128 + dd) * 128 + j];
        }
        Wfrag[gid] = f2bf(acc);
        Wcat32[k * 128 + j] = acc;
    } else if (gid < 512 * 128 + 128) {
        int j = gid - 512 * 128;
        float acc = 0.f;
        for (int dd = 0; dd < 128; ++dd)
            acc += b_msg[dd] * W_upd[(128 + dd) * 128 + j];
        bv[j] = acc;
    }
}

__global__ void k_hcvt(const float* __restrict__ h, ushort* __restrict__ h16) {
    int gid = blockIdx.x * 256 + threadIdx.x;
    if (gid >= N_NODES * D / 4) return;
    f32x4 v = *(const f32x4*)(h + (size_t)gid * 4);
    ushort4 u;
    u.x = f2bf(v[0]); u.y = f2bf(v[1]); u.z = f2bf(v[2]); u.w = f2bf(v[3]);
    *(ushort4*)(h16 + (size_t)gid * 4) = u;
}

__global__ void k_bucket(const int* __restrict__ eidx,
                         int* __restrict__ cnt,
                         int* __restrict__ ovf,
                         int2* __restrict__ elist2)
{
    int e = blockIdx.x * 256 + threadIdx.x;
    if (e >= N_EDGES) return;
    int s = eidx[e];
    int r = eidx[N_EDGES + e];
    int slot = atomicAdd(cnt + r, 1);
    if (slot < MAXDEG) {
        elist2[(size_t)r * MAXDEG + slot] = make_int2(e, s);
    } else {
        int p = atomicAdd(cnt + N_NODES, 1);
        if (p < OVF_CAP) ovf[p] = e;
    }
}

// One wave per node, no barriers. h gathered as bf16 (4B/lane), ea fp32 nt.
// Output: Sea16[n][0..127]=S, [128..255]=Ea (bf16); deg[n].
__global__ __launch_bounds__(256, 8) void k_gather2(
    const ushort* __restrict__ h16,
    const float* __restrict__ ea,
    const int* __restrict__ cnt,
    const int2* __restrict__ elist2,
    ushort* __restrict__ Sea16,
    float* __restrict__ deg)
{
    int gid = blockIdx.x * 256 + threadIdx.x;
    int n = gid >> 6;
    int lane = gid & 63;
    if (n >= N_NODES) return;
    const int c = cnt[n];
    const int m = c < MAXDEG ? c : MAXDEG;
    int2 es = make_int2(0, 0);
    if (lane < m) es = elist2[(size_t)n * MAXDEG + lane];

    float Sx = 0.f, Sy = 0.f, Ex = 0.f, Ey = 0.f;
    int t = 0;
    for (; t + 4 <= m; t += 4) {
        int e0 = __shfl(es.x, t + 0), s0 = __shfl(es.y, t + 0);
        int e1 = __shfl(es.x, t + 1), s1 = __shfl(es.y, t + 1);
        int e2 = __shfl(es.x, t + 2), s2 = __shfl(es.y, t + 2);
        int e3 = __shfl(es.x, t + 3), s3 = __shfl(es.y, t + 3);
        unsigned a0 = *(const unsigned*)(h16 + (size_t)s0 * D + lane * 2);
        unsigned a1 = *(const unsigned*)(h16 + (size_t)s1 * D + lane * 2);
        unsigned a2 = *(const unsigned*)(h16 + (size_t)s2 * D + lane * 2);
        unsigned a3 = *(const unsigned*)(h16 + (size_t)s3 * D + lane * 2);
        f32x2 b0 = nt_load2(ea + (size_t)e0 * D + lane * 2);
        f32x2 b1 = nt_load2(ea + (size_t)e1 * D + lane * 2);
        f32x2 b2 = nt_load2(ea + (size_t)e2 * D + lane * 2);
        f32x2 b3 = nt_load2(ea + (size_t)e3 * D + lane * 2);
        Sx += (bf2f((ushort)a0) + bf2f((ushort)a1)) + (bf2f((ushort)a2) + bf2f((ushort)a3));
        Sy += (bf2f((ushort)(a0 >> 16)) + bf2f((ushort)(a1 >> 16))) +
              (bf2f((ushort)(a2 >> 16)) + bf2f((ushort)(a3 >> 16)));
        Ex += (b0[0] + b1[0]) + (b2[0] + b3[0]);
        Ey += (b0[1] + b1[1]) + (b2[1] + b3[1]);
    }
    for (; t < m; ++t) {
        int e = __shfl(es.x, t), s = __shfl(es.y, t);
        unsigned a = *(const unsigned*)(h16 + (size_t)s * D + lane * 2);
        f32x2 b = nt_load2(ea + (size_t)e * D + lane * 2);
        Sx += bf2f((ushort)a); Sy += bf2f((ushort)(a >> 16));
        Ex += b[0]; Ey += b[1];
    }

    unsigned sp = (unsigned)f2bf(Sx) | ((unsigned)f2bf(Sy) << 16);
    unsigned ep = (unsigned)f2bf(Ex) | ((unsigned)f2bf(Ey) << 16);
    *(unsigned*)(Sea16 + (size_t)n * 256 + lane * 2) = sp;
    *(unsigned*)(Sea16 + (size_t)n * 256 + 128 + lane * 2) = ep;
    if (lane == 0) deg[n] = (float)c;
}

// Streaming MFMA GEMM: X=[h|S|deg*h|Ea] (bf16) @ Wfrag. BM=32 nodes/block.
__global__ __launch_bounds__(256, 4) void k_gemm(
    const ushort* __restrict__ h16,
    const ushort* __restrict__ Sea16,
    const float* __restrict__ deg,
    const ushort* __restrict__ Wfrag,
    const float* __restrict__ bv,
    const float* __restrict__ b_upd,
    float* __restrict__ out)
{
    __shared__ ushort Xs[BM][520];
    __shared__ float degL[BM];
    const int tid = threadIdx.x;
    const int n0 = blockIdx.x * BM;
    if (tid < BM) degL[tid] = deg[n0 + tid];

    for (int q = tid; q < BM * 64; q += 256) {
        int i = q >> 6, j = q & 63;   // j = ushort8 chunk of the 512-col row
        int n = n0 + i;
        uint4 v;
        if (j < 16) {
            v = *(const uint4*)(h16 + (size_t)n * D + j * 8);
        } else if (j < 32) {
            v = *(const uint4*)(Sea16 + (size_t)n * 256 + (j - 16) * 8);
        } else if (j < 48) {
            uint4 a = *(const uint4*)(h16 + (size_t)n * D + (j - 32) * 8);
            float dv = deg[n];
            v.x = mulpack2(a.x, dv); v.y = mulpack2(a.y, dv);
            v.z = mulpack2(a.z, dv); v.w = mulpack2(a.w, dv);
        } else {
            v = *(const uint4*)(Sea16 + (size_t)n * 256 + 128 + (j - 48) * 8);
        }
        *(uint4*)&Xs[i][j * 8] = v;
    }
    __syncthreads();

    const int lane = tid & 63;
    const int wv = tid >> 6;
    const int rb = wv >> 1;
    const int cbg = wv & 1;
    const int arow = rb * 16 + (lane & 15);
    const int koff = (lane >> 4) * 8;

    f32x4 acc[4] = {};
    for (int kb = 0; kb < 16; ++kb) {
        bf16x8 a = *(const bf16x8*)&Xs[arow][kb * 32 + koff];
        #pragma unroll
        for (int cc = 0; cc < 4; ++cc) {
            int fb = kb * 8 + cbg * 4 + cc;
            bf16x8 b = *(const bf16x8*)(Wfrag + ((size_t)fb * 64 + lane) * 8);
            acc[cc] = __builtin_amdgcn_mfma_f32_16x16x32_bf16(a, b, acc[cc], 0, 0, 0);
        }
    }

    const int r0 = (lane >> 4) * 4;
    #pragma unroll
    for (int cc = 0; cc < 4; ++cc) {
        int col = cbg * 64 + cc * 16 + (lane & 15);
        float bvv = bv[col];
        float buv = b_upd[col];
        #pragma unroll
        for (int r = 0; r < 4; ++r) {
            int rl = rb * 16 + r0 + r;
            out[(size_t)(n0 + rl) * D + col] = acc[cc][r] + degL[rl] * bvv + buv;
        }
    }
}

// Overflow edges (expected 0): add h_s@(W1@Wu2) + ea@(W3@Wu2) into out[rec].
__global__ void k_ovf(const float* __restrict__ h,
                      const int* __restrict__ eidx,
                      const float* __restrict__ ea,
                      const int* __restrict__ cnt,
                      const int* __restrict__ ovf,
                      const float* __restrict__ Wcat32,
                      float* __restrict__ out)
{
    int ncnt = cnt[N_NODES];
    if (ncnt > OVF_CAP) ncnt = OVF_CAP;
    if (ncnt <= 0) return;
    int lane = threadIdx.x & 63;
    int w = threadIdx.x >> 6;
    for (int i = w; i < ncnt; i += 4) {
        int e = ovf[i];
        int s = eidx[e];
        int r = eidx[N_EDGES + e];
        float acc0 = 0.f, acc1 = 0.f;
        for (int dd = 0; dd < 128; ++dd) {
            float hs = h[(size_t)s * D + dd];
            float ev = ea[(size_t)e * D + dd];
            acc0 += hs * Wcat32[(128 + dd) * 128 + lane * 2]     + ev * Wcat32[(384 + dd) * 128 + lane * 2];
            acc1 += hs * Wcat32[(128 + dd) * 128 + lane * 2 + 1] + ev * Wcat32[(384 + dd) * 128 + lane * 2 + 1];
        }
        atomicAdd(out + (size_t)r * D + lane * 2 + 0, acc0);
        atomicAdd(out + (size_t)r * D + lane * 2 + 1, acc1);
    }
}

extern "C" void kernel_launch(void* const* d_in, const int* in_sizes, int n_in,
                              void* d_out, int out_size, void* d_ws, size_t ws_size,
                              hipStream_t stream)
{
    const float* h     = (const float*)d_in[0];
    const int*   eidx  = (const int*)d_in[1];
    const float* eattr = (const float*)d_in[2];
    const float* W_msg = (const float*)d_in[3];
    const float* b_msg = (const float*)d_in[4];
    const float* W_upd = (const float*)d_in[5];
    const float* b_upd = (const float*)d_in[6];
    float* out = (float*)d_out;

    char* base = (char*)d_ws;
    ushort* Wfrag  = (ushort*)(base);
    float*  Wcat32 = (float*)(base + 131072);
    float*  bv     = (float*)(base + 393216);
    float*  deg    = (float*)(base + 393728);
    int*    cnt    = (int*)(base + 793728);
    int*    ovf    = (int*)(base + 1193984);
    int2*   elist2 = (int2*)(base + 1210368);
    ushort* h16    = (ushort*)(base + 52410368);
    ushort* Sea16  = (ushort*)(base + 78010368);

    k_zero<<<(N_NODES + 1 + 255) / 256, 256, 0, stream>>>(cnt);
    k_build_w<<<(512 * 128 + 128 + 255) / 256, 256, 0, stream>>>(W_msg, b_msg, W_upd, Wfrag, Wcat32, bv);
    k_hcvt<<<(N_NODES * D / 4 + 255) / 256, 256, 0, stream>>>(h, h16);
    k_bucket<<<(N_EDGES + 255) / 256, 256, 0, stream>>>(eidx, cnt, ovf, elist2);
    k_gather2<<<(N_NODES * 64 + 255) / 256, 256, 0, stream>>>(h16, eattr, cnt, elist2, Sea16, deg);
    k_gemm<<<N_NODES / BM, 256, 0, stream>>>(h16, Sea16, deg, Wfrag, bv, b_upd, out);
    k_ovf<<<1, 256, 0, stream>>>(h, eidx, eattr, cnt, ovf, Wcat32, out);
}

// Round 7
// 172.123 us; speedup vs baseline: 1.1782x; 1.1782x over previous
//
#include <hip/hip_runtime.h>

#define N_NODES 100000
#define N_EDGES 600000
#define D 128
#define MAXDEG 64
#define OVF_CAP 4096
#define BM 16              // nodes per block

typedef __attribute__((ext_vector_type(8))) short bf16x8;
typedef __attribute__((ext_vector_type(4))) float f32x4;

static __device__ inline ushort f2bf(float f) {
    unsigned x = __float_as_uint(f);
    unsigned r = (x + 0x7fffu + ((x >> 16) & 1u)) >> 16;  // RNE
    return (ushort)r;
}
static __device__ inline f32x4 nt_load4(const float* p) {
    return __builtin_nontemporal_load((const f32x4*)p);
}
static __device__ inline ushort4 pack4(f32x4 v) {
    ushort4 u;
    u.x = f2bf(v[0]); u.y = f2bf(v[1]); u.z = f2bf(v[2]); u.w = f2bf(v[3]);
    return u;
}

// ws layout (byte offsets):
//   0        Wfrag  ushort[512*128]  bf16 fused weight, MFMA B-frag order
//   131072   Wcat32 float[512*128]   fp32 fused weight (overflow path)
//   393216   bv     float[128]
//   393728   cnt    int[N+1] (+pad to 100002)
//   794736   ovf    int[OVF_CAP]
//   811120   elist2 int2[N*MAXDEG]
//
// out[n] = [h[n] | S[n] | deg[n]*h[n] | Ea[n]] @ Wcat + deg[n]*bv + b_upd
// Wfrag[(kb*8+cb)*512 + l*8 + i] = Wcat[kb*32+(l>>4)*8+i][cb*16+(l&15)]
// Wcat rows: 0..127 = Wu1; 128..255 = W1@Wu2; 256..383 = W2@Wu2; 384..511 = W3@Wu2
// bv = b_msg @ Wu2

__global__ void k_zero(int* __restrict__ cnt) {
    int i = blockIdx.x * 256 + threadIdx.x;
    if (i < N_NODES + 1) cnt[i] = 0;
}

__global__ void k_build_w(const float* __restrict__ W_msg,
                          const float* __restrict__ b_msg,
                          const float* __restrict__ W_upd,
                          ushort* __restrict__ Wfrag,
                          float* __restrict__ Wcat32,
                          float* __restrict__ bv)
{
    int gid = blockIdx.x * 256 + threadIdx.x;
    if (gid < 512 * 128) {
        int i = gid & 7;
        int l = (gid >> 3) & 63;
        int fb = gid >> 9;          // kb*8 + cb
        int kb = fb >> 3, cb = fb & 7;
        int k = kb * 32 + ((l >> 4) * 8) + i;
        int j = cb * 16 + (l & 15);
        float acc;
        if (k < 128) {
            acc = W_upd[k * 128 + j];
        } else {
            int r = k - 128;
            acc = 0.f;
            #pragma unroll 4
            for (int dd = 0; dd < 128; ++dd)
                acc += W_msg[r * 128 + dd] * W_upd[(128 + dd) * 128 + j];
        }
        Wfrag[gid] = f2bf(acc);
        Wcat32[k * 128 + j] = acc;
    } else if (gid < 512 * 128 + 128) {
        int j = gid - 512 * 128;
        float acc = 0.f;
        for (int dd = 0; dd < 128; ++dd)
            acc += b_msg[dd] * W_upd[(128 + dd) * 128 + j];
        bv[j] = acc;
    }
}

__global__ void k_bucket(const int* __restrict__ eidx,
                         int* __restrict__ cnt,
                         int* __restrict__ ovf,
                         int2* __restrict__ elist2)
{
    int e = blockIdx.x * 256 + threadIdx.x;
    if (e >= N_EDGES) return;
    int s = eidx[e];
    int r = eidx[N_EDGES + e];
    int slot = atomicAdd(cnt + r, 1);
    if (slot < MAXDEG) {
        elist2[(size_t)r * MAXDEG + slot] = make_int2(e, s);
    } else {
        int p = atomicAdd(cnt + N_NODES, 1);
        if (p < OVF_CAP) ovf[p] = e;
    }
}

// Fused gather + GEMM. 256 thr = 4 waves, BM=16 nodes/block (4 per wave).
// Gather: half-wave per edge — lanes 0-31 load edge t's 512B row as float4,
// lanes 32-63 load edge t+1's row in the SAME instruction (2 rows / vmcnt slot).
// Cross-half __shfl_xor(32) reduce merges even/odd-edge partial sums per node.
__global__ __launch_bounds__(256, 8) void k_fused(
    const float* __restrict__ h,
    const float* __restrict__ ea,
    const int* __restrict__ cnt,
    const int2* __restrict__ elist2,
    const ushort* __restrict__ Wfrag,
    const float* __restrict__ bv,
    const float* __restrict__ b_upd,
    float* __restrict__ out)
{
    __shared__ ushort Xs[BM][520];   // bf16 X tile, padded row
    __shared__ float degL[BM];
    const int tid = threadIdx.x;
    const int lane = tid & 63;
    const int half = lane >> 5;      // which edge of the pair
    const int hl = lane & 31;        // float4 column index (cols 4*hl..+3)
    const int wv = tid >> 6;
    const int n0 = blockIdx.x * BM;
    const int nb = n0 + wv * 4;

    // pipeline: preload node 0's metadata (elist rows always in-bounds; unused lanes harmless)
    int2 es = elist2[(size_t)nb * MAXDEG + lane];
    int   c = cnt[nb];

    for (int u = 0; u < 4; ++u) {
        const int i = wv * 4 + u;
        const int n = nb + u;
        int2 es_n; int c_n;
        if (u < 3) {
            es_n = elist2[(size_t)(n + 1) * MAXDEG + lane];
            c_n  = cnt[n + 1];
        }
        const int m = c < MAXDEG ? c : MAXDEG;

        f32x4 aS = {0.f, 0.f, 0.f, 0.f};
        f32x4 aE = {0.f, 0.f, 0.f, 0.f};
        int t = 0;
        for (; t + 4 <= m; t += 4) {          // 4 edges per iter, 4 load insts
            int iA = t + half, iB = t + 2 + half;
            int eA = __shfl(es.x, iA), sA = __shfl(es.y, iA);
            int eB = __shfl(es.x, iB), sB = __shfl(es.y, iB);
            f32x4 a0 = *(const f32x4*)(h + (size_t)sA * D + hl * 4);
            f32x4 b0 = nt_load4(ea + (size_t)eA * D + hl * 4);
            f32x4 a1 = *(const f32x4*)(h + (size_t)sB * D + hl * 4);
            f32x4 b1 = nt_load4(ea + (size_t)eB * D + hl * 4);
            aS += a0 + a1;
            aE += b0 + b1;
        }
        for (; t < m; t += 2) {               // tail: 2 edges per iter, guarded
            int idx = t + half;
            if (idx < m) {
                int eA = __shfl(es.x, idx), sA = __shfl(es.y, idx);
                f32x4 a0 = *(const f32x4*)(h + (size_t)sA * D + hl * 4);
                f32x4 b0 = nt_load4(ea + (size_t)eA * D + hl * 4);
                aS += a0;
                aE += b0;
            }
        }
        // merge even-edge (half 0) and odd-edge (half 1) partial sums
        aS[0] += __shfl_xor(aS[0], 32); aS[1] += __shfl_xor(aS[1], 32);
        aS[2] += __shfl_xor(aS[2], 32); aS[3] += __shfl_xor(aS[3], 32);
        aE[0] += __shfl_xor(aE[0], 32); aE[1] += __shfl_xor(aE[1], 32);
        aE[2] += __shfl_xor(aE[2], 32); aE[3] += __shfl_xor(aE[3], 32);

        const float dv = (float)c;
        f32x4 hn = *(const f32x4*)(h + (size_t)n * D + hl * 4);
        if (half == 0) {
            *(ushort4*)&Xs[i][      hl * 4] = pack4(hn);
            *(ushort4*)&Xs[i][128 + hl * 4] = pack4(aS);
        } else {
            f32x4 dh = {dv * hn[0], dv * hn[1], dv * hn[2], dv * hn[3]};
            *(ushort4*)&Xs[i][256 + hl * 4] = pack4(dh);
            *(ushort4*)&Xs[i][384 + hl * 4] = pack4(aE);
        }
        if (lane == 0) degL[i] = dv;
        es = es_n; c = c_n;
    }
    __syncthreads();

    // MFMA: [16,512]@[512,128]; wave wv does cols 32*wv..+31
    const int arow = lane & 15;
    const int koff = (lane >> 4) * 8;

    f32x4 acc[2] = {};
    for (int kb = 0; kb < 16; ++kb) {
        bf16x8 a = *(const bf16x8*)&Xs[arow][kb * 32 + koff];
        #pragma unroll
        for (int cc = 0; cc < 2; ++cc) {
            int fb = kb * 8 + wv * 2 + cc;
            bf16x8 b = *(const bf16x8*)(Wfrag + ((size_t)fb * 64 + lane) * 8);
            acc[cc] = __builtin_amdgcn_mfma_f32_16x16x32_bf16(a, b, acc[cc], 0, 0, 0);
        }
    }

    const int r0 = (lane >> 4) * 4;
    #pragma unroll
    for (int cc = 0; cc < 2; ++cc) {
        int col = wv * 32 + cc * 16 + (lane & 15);
        float bvv = bv[col];
        float buv = b_upd[col];
        #pragma unroll
        for (int r = 0; r < 4; ++r) {
            int rl = r0 + r;
            out[(size_t)(n0 + rl) * D + col] = acc[cc][r] + degL[rl] * bvv + buv;
        }
    }
}

// Overflow edges (expected 0): add h_s@(W1@Wu2) + ea@(W3@Wu2) into out[rec].
__global__ void k_ovf(const float* __restrict__ h,
                      const int* __restrict__ eidx,
                      const float* __restrict__ ea,
                      const int* __restrict__ cnt,
                      const int* __restrict__ ovf,
                      const float* __restrict__ Wcat32,
                      float* __restrict__ out)
{
    int ncnt = cnt[N_NODES];
    if (ncnt > OVF_CAP) ncnt = OVF_CAP;
    if (ncnt <= 0) return;
    int lane = threadIdx.x & 63;
    int w = threadIdx.x >> 6;
    for (int i = w; i < ncnt; i += 4) {
        int e = ovf[i];
        int s = eidx[e];
        int r = eidx[N_EDGES + e];
        float acc0 = 0.f, acc1 = 0.f;
        for (int dd = 0; dd < 128; ++dd) {
            float hs = h[(size_t)s * D + dd];
            float ev = ea[(size_t)e * D + dd];
            acc0 += hs * Wcat32[(128 + dd) * 128 + lane * 2]     + ev * Wcat32[(384 + dd) * 128 + lane * 2];
            acc1 += hs * Wcat32[(128 + dd) * 128 + lane * 2 + 1] + ev * Wcat32[(384 + dd) * 128 + lane * 2 + 1];
        }
        atomicAdd(out + (size_t)r * D + lane * 2 + 0, acc0);
        atomicAdd(out + (size_t)r * D + lane * 2 + 1, acc1);
    }
}

extern "C" void kernel_launch(void* const* d_in, const int* in_sizes, int n_in,
                              void* d_out, int out_size, void* d_ws, size_t ws_size,
                              hipStream_t stream)
{
    const float* h     = (const float*)d_in[0];
    const int*   eidx  = (const int*)d_in[1];
    const float* eattr = (const float*)d_in[2];
    const float* W_msg = (const float*)d_in[3];
    const float* b_msg = (const float*)d_in[4];
    const float* W_upd = (const float*)d_in[5];
    const float* b_upd = (const float*)d_in[6];
    float* out = (float*)d_out;

    char* base = (char*)d_ws;
    ushort* Wfrag  = (ushort*)(base);
    float*  Wcat32 = (float*)(base + 131072);
    float*  bv     = (float*)(base + 393216);
    int*    cnt    = (int*)(base + 393728);      // N_NODES+1 used (+pad)
    int*    ovf    = (int*)(base + 794736);
    int2*   elist2 = (int2*)(base + 811120);

    k_zero<<<(N_NODES + 1 + 255) / 256, 256, 0, stream>>>(cnt);
    k_build_w<<<(512 * 128 + 128 + 255) / 256, 256, 0, stream>>>(W_msg, b_msg, W_upd, Wfrag, Wcat32, bv);
    k_bucket<<<(N_EDGES + 255) / 256, 256, 0, stream>>>(eidx, cnt, ovf, elist2);
    k_fused<<<N_NODES / BM, 256, 0, stream>>>(h, eattr, cnt, elist2, Wfrag, bv, b_upd, out);
    k_ovf<<<1, 256, 0, stream>>>(h, eidx, eattr, cnt, ovf, Wcat32, out);
}